// Round 1
// baseline (1227.413 us; speedup 1.0000x reference)
//
#include <hip/hip_runtime.h>
#include <hip/hip_bf16.h>
#include <stdint.h>

// Problem constants (B=16, NW=256, WS=8, FD=96)
#define T_TOK 4096        // B*NW tokens
#define DD    6144        // WS*WS*FD
#define MIDD  512
#define NEXP  16

typedef __attribute__((ext_vector_type(8))) __bf16 bf16x8;
typedef __attribute__((ext_vector_type(4))) float  f32x4;

__device__ __forceinline__ unsigned short f2bf(float f) {
  unsigned int u = __builtin_bit_cast(unsigned int, f);
  u += 0x7fffu + ((u >> 16) & 1u);   // round-to-nearest-even
  return (unsigned short)(u >> 16);
}

__device__ __forceinline__ void gload16(const void* g, void* l) {
  __builtin_amdgcn_global_load_lds((__attribute__((address_space(1))) void*)g,
                                   (__attribute__((address_space(3))) void*)l,
                                   16, 0, 0);
}

// ---------- kernel 1: x fp32 -> bf16 (no transpose) ----------
__global__ __launch_bounds__(256) void k_cvt_x(const float4* __restrict__ x,
                                               ushort4* __restrict__ xb, int n4) {
  int i = blockIdx.x * blockDim.x + threadIdx.x;
  const int stride = gridDim.x * blockDim.x;
  for (; i < n4; i += stride) {
    const float4 v = x[i];
    ushort4 o;
    o.x = f2bf(v.x); o.y = f2bf(v.y); o.z = f2bf(v.z); o.w = f2bf(v.w);
    xb[i] = o;
  }
}

// ---------- kernel 2: w1 [NE][D][MID] fp32 -> W1T [NE][MID][D] bf16 ----------
__global__ __launch_bounds__(256) void k_trc_w1(const float* __restrict__ w1,
                                                unsigned short* __restrict__ w1t) {
  __shared__ float tile[32][33];           // +1 pad breaks bank aliasing
  const int n  = blockIdx.z;
  const int d0 = blockIdx.y * 32;
  const int m0 = blockIdx.x * 32;
  const int r  = threadIdx.x >> 3;         // 0..31
  const int c4 = threadIdx.x & 7;          // 0..7 (float4 in fast dim)

  const float4 v = *(const float4*)(w1 + (size_t)n * DD * MIDD +
                                    (size_t)(d0 + r) * MIDD + m0 + c4 * 4);
  tile[r][c4 * 4 + 0] = v.x;
  tile[r][c4 * 4 + 1] = v.y;
  tile[r][c4 * 4 + 2] = v.z;
  tile[r][c4 * 4 + 3] = v.w;
  __syncthreads();
  ushort4 o;
  o.x = f2bf(tile[c4 * 4 + 0][r]);
  o.y = f2bf(tile[c4 * 4 + 1][r]);
  o.z = f2bf(tile[c4 * 4 + 2][r]);
  o.w = f2bf(tile[c4 * 4 + 3][r]);
  *(ushort4*)(w1t + (size_t)n * MIDD * DD + (size_t)(m0 + r) * DD + d0 + c4 * 4) = o;
}

// ---------- kernel 3: fused GEMM + bias/ReLU/w2-reduce epilogue ----------
// C[t, ne*512+m] = relu(Xb[t,:] . W1T[ne][m,:] + b1) ; e_part = per-tile w2-dot
// 128x128 tile, BK=32, 4 waves (2x2 of 64x64), m97 structure.
// LDS tile layout: [kb=4][row=128][8 bf16] so each 16-lane fragment read is a
// contiguous 256B stripe -> conflict-free ds_read_b128, and global_load_lds's
// linear lane order matches (wave w stages kb=w).
__global__ __launch_bounds__(256) void k_gemm(const unsigned short* __restrict__ Xb,
                                              const unsigned short* __restrict__ W1T,
                                              const float* __restrict__ b1,
                                              const float* __restrict__ w2,
                                              float* __restrict__ e_part) {
  __shared__ char lds[16384];
  char* ldsA = lds;            // 8 KiB
  char* ldsB = lds + 8192;     // 8 KiB

  const int tid  = threadIdx.x;
  const int wid  = tid >> 6;
  const int lane = tid & 63;
  const int bn   = blockIdx.x;       // 0..63  (col tiles)
  const int bm   = blockIdx.y;       // 0..31  (row tiles)
  const int row0 = bm * 128;
  const int col0 = bn * 128;
  const int ne   = col0 >> 9;        // expert (512 cols each; 128|512)
  const int m0   = col0 & 511;
  const int wr = wid >> 1, wc = wid & 1;
  const int kb = lane >> 4, lr = lane & 15;

  f32x4 acc[4][4] = {};

  const unsigned short* Ag = Xb + (size_t)row0 * DD + wid * 8;
  const unsigned short* Bg = W1T + ((size_t)ne * MIDD + m0) * DD + wid * 8;
  char* ldsAw = ldsA + wid * 2048;
  char* ldsBw = ldsB + wid * 2048;

  for (int k0 = 0; k0 < DD; k0 += 32) {
    __syncthreads();                              // prev compute done
    gload16(Ag + (size_t)lane        * DD + k0, ldsAw);
    gload16(Ag + (size_t)(64 + lane) * DD + k0, ldsAw + 1024);
    gload16(Bg + (size_t)lane        * DD + k0, ldsBw);
    gload16(Bg + (size_t)(64 + lane) * DD + k0, ldsBw + 1024);
    __syncthreads();                              // vmcnt(0) drained here

    bf16x8 af[4], bfr[4];
#pragma unroll
    for (int m = 0; m < 4; ++m)
      af[m] = *(const bf16x8*)(ldsA + kb * 2048 + (wr * 64 + m * 16 + lr) * 16);
#pragma unroll
    for (int nn = 0; nn < 4; ++nn)
      bfr[nn] = *(const bf16x8*)(ldsB + kb * 2048 + (wc * 64 + nn * 16 + lr) * 16);
#pragma unroll
    for (int m = 0; m < 4; ++m)
#pragma unroll
      for (int nn = 0; nn < 4; ++nn)
        acc[m][nn] = __builtin_amdgcn_mfma_f32_16x16x32_bf16(af[m], bfr[nn],
                                                             acc[m][nn], 0, 0, 0);
  }

  // ---- epilogue: h = relu(acc + b1); s = sum_m h*w2 ; partial per (row, part)
  const int part = ((bn & 3) << 1) | wc;   // 8 col-partials per (t, expert)
  float b1v[4], w2v[4];
#pragma unroll
  for (int bj = 0; bj < 4; ++bj) {
    const int mcol = m0 + wc * 64 + bj * 16 + lr;
    b1v[bj] = b1[ne * MIDD + mcol];
    w2v[bj] = w2[ne * MIDD + mcol];
  }
#pragma unroll
  for (int ai = 0; ai < 4; ++ai) {
#pragma unroll
    for (int i = 0; i < 4; ++i) {
      float s = 0.f;
#pragma unroll
      for (int bj = 0; bj < 4; ++bj) {
        float h = acc[ai][bj][i] + b1v[bj];   // C row=(lane>>4)*4+i, col=lane&15
        h = fmaxf(h, 0.f);
        s += h * w2v[bj];
      }
      s += __shfl_xor(s, 1);
      s += __shfl_xor(s, 2);
      s += __shfl_xor(s, 4);
      s += __shfl_xor(s, 8);
      if (lr == 0) {
        const int row = row0 + wr * 64 + ai * 16 + kb * 4 + i;
        e_part[((size_t)row * NEXP + ne) * 8 + part] = s;
      }
    }
  }
}

// ---------- kernel 4: gating logits, d-split x8 ----------
// block = 256 thr = 64 tokens x 4 lanes; lane owns 4 experts; fp32 x for accuracy
__global__ __launch_bounds__(256) void k_gate(const float* __restrict__ x,
                                              const float* __restrict__ gw,
                                              float* __restrict__ l_part) {
  const int tl = threadIdx.x >> 2, ng = threadIdx.x & 3;
  const int tg = blockIdx.x >> 3, ds = blockIdx.x & 7;
  const int t  = tg * 64 + tl;
  const float* xp  = x  + (size_t)t * DD + ds * 768;
  const float* gwp = gw + (size_t)(ds * 768) * NEXP + ng * 4;
  float a[4] = {0.f, 0.f, 0.f, 0.f};
  for (int c = 0; c < 768; c += 4) {
    const float4 xv = *(const float4*)(xp + c);
    const float xs[4] = {xv.x, xv.y, xv.z, xv.w};
#pragma unroll
    for (int j = 0; j < 4; ++j) {
      const float4 g4 = *(const float4*)(gwp + (size_t)(c + j) * NEXP);
      a[0] += xs[j] * g4.x; a[1] += xs[j] * g4.y;
      a[2] += xs[j] * g4.z; a[3] += xs[j] * g4.w;
    }
  }
  float* lp = l_part + ((size_t)t * NEXP + ng * 4) * 8 + ds;
  lp[0] = a[0]; lp[8] = a[1]; lp[16] = a[2]; lp[24] = a[3];
}

// ---------- kernel 5: combine: softmax(logits) . e -> sigmoid ----------
__global__ __launch_bounds__(256) void k_combine(const float* __restrict__ l_part,
                                                 const float* __restrict__ e_part,
                                                 const float* __restrict__ gb,
                                                 const float* __restrict__ b2,
                                                 float* __restrict__ out) {
  const int tl = threadIdx.x >> 4, n = threadIdx.x & 15;
  const int t  = blockIdx.x * 16 + tl;
  const float4* lp = (const float4*)(l_part + ((size_t)t * NEXP + n) * 8);
  const float4 l0 = lp[0], l1 = lp[1];
  const float logit = l0.x + l0.y + l0.z + l0.w + l1.x + l1.y + l1.z + l1.w + gb[n];
  const float4* ep = (const float4*)(e_part + ((size_t)t * NEXP + n) * 8);
  const float4 e0 = ep[0], e1 = ep[1];
  const float ev = e0.x + e0.y + e0.z + e0.w + e1.x + e1.y + e1.z + e1.w + b2[n];
  float m = logit;
  m = fmaxf(m, __shfl_xor(m, 1));
  m = fmaxf(m, __shfl_xor(m, 2));
  m = fmaxf(m, __shfl_xor(m, 4));
  m = fmaxf(m, __shfl_xor(m, 8));
  const float p = __expf(logit - m);
  float pe = p * ev, pz = p;
  pe += __shfl_xor(pe, 1); pz += __shfl_xor(pz, 1);
  pe += __shfl_xor(pe, 2); pz += __shfl_xor(pz, 2);
  pe += __shfl_xor(pe, 4); pz += __shfl_xor(pz, 4);
  pe += __shfl_xor(pe, 8); pz += __shfl_xor(pz, 8);
  if (n == 0) {
    const float z = pe / pz;
    out[t] = 1.f / (1.f + __expf(-z));
  }
}

extern "C" void kernel_launch(void* const* d_in, const int* in_sizes, int n_in,
                              void* d_out, int out_size, void* d_ws, size_t ws_size,
                              hipStream_t stream) {
  const float* x  = (const float*)d_in[0];
  const float* w1 = (const float*)d_in[1];
  const float* b1 = (const float*)d_in[2];
  const float* w2 = (const float*)d_in[3];
  const float* b2 = (const float*)d_in[4];
  const float* gw = (const float*)d_in[5];
  const float* gb = (const float*)d_in[6];
  float* out = (float*)d_out;

  // workspace layout (needs ~149 MiB)
  char* ws = (char*)d_ws;
  unsigned short* Xb  = (unsigned short*)ws;                 // 4096*6144*2   = 50331648 B
  unsigned short* W1T = (unsigned short*)(ws + 50331648);    // 16*512*6144*2 = 100663296 B
  float* e_part = (float*)(ws + 150994944);                  // 4096*16*8*4   = 2097152 B
  float* l_part = (float*)(ws + 153092096);                  // 4096*16*8*4   = 2097152 B

  k_cvt_x<<<2048, 256, 0, stream>>>((const float4*)x, (ushort4*)Xb, (T_TOK * DD) / 4);
  k_trc_w1<<<dim3(MIDD / 32, DD / 32, NEXP), 256, 0, stream>>>(w1, W1T);
  k_gemm<<<dim3(64, 32), 256, 0, stream>>>(Xb, W1T, b1, w2, e_part);
  k_gate<<<512, 256, 0, stream>>>(x, gw, l_part);
  k_combine<<<256, 256, 0, stream>>>(l_part, e_part, gb, b2, out);
}